// Round 9
// baseline (636.074 us; speedup 1.0000x reference)
//
#include <hip/hip_runtime.h>
#include <math.h>

#ifndef M_PI
#define M_PI 3.14159265358979323846
#endif

#define N_FFT       512
#define N_BINS      257
#define N_FILTERS   128
#define OUTPUT_SIZE 262144
#define N_TIMESTEPS 128

typedef int int4v __attribute__((ext_vector_type(4)));

// ---- ordered-uint64 encoding for deterministic double atomic min/max ----
__device__ __forceinline__ unsigned long long enc_d(double f) {
    unsigned long long u = (unsigned long long)__double_as_longlong(f);
    return (u & 0x8000000000000000ull) ? ~u : (u | 0x8000000000000000ull);
}
__device__ __forceinline__ double dec_d(unsigned long long e) {
    unsigned long long u = (e & 0x8000000000000000ull) ? (e ^ 0x8000000000000000ull) : ~e;
    return __longlong_as_double((long long)u);
}

// ============================================================================
// K1a: DFT, one block per bin (257 blocks x 64 threads) — verified R7/R8.
//   Block 0 inits the minmax atomic slots (consumed by k2 later in stream).
// ============================================================================
__global__ __launch_bounds__(64) void k1a_dft(
    const float* __restrict__ audio, float* __restrict__ mag,
    unsigned long long* __restrict__ minmax)
{
    __shared__ double sre[64];
    __shared__ double sim[64];

    const int b    = blockIdx.x;     // bin 0..256
    const int lane = threadIdx.x;    // 0..63

    double re = 0.0, im = 0.0;
    #pragma unroll
    for (int j = 0; j < 8; ++j) {
        const int n = lane * 8 + j;              // rfft(n=512): first 512 samples
        const int m = (b * n) & (N_FFT - 1);
        double s, c;
        sincos((-2.0 * M_PI * (double)m) / (double)N_FFT, &s, &c);
        const double a = (double)audio[n];
        re += a * c;
        im += a * s;
    }
    sre[lane] = re;
    sim[lane] = im;
    __syncthreads();
    #pragma unroll
    for (int s = 32; s > 0; s >>= 1) {
        if (lane < s) {
            sre[lane] += sre[lane + s];
            sim[lane] += sim[lane + s];
        }
        __syncthreads();
    }
    if (lane == 0) {
        mag[b] = (float)sqrt(sre[0] * sre[0] + sim[0] * sim[0]);
        if (b == 0) {
            minmax[0] = 0xFFFFFFFFFFFFFFFFull;  // min slot
            minmax[1] = 0ull;                   // max slot
        }
    }
}

// ============================================================================
// K1b: post-DFT front-end (1 block x 256 threads) — verified R7 numerics.
//   Separate tiny kernel again: fusing this into every k2 block (R8) cost
//   k2 ~+29 us (pow + 257-iter dependent fp64 chain x 1024 blocks).
// ============================================================================
__global__ __launch_bounds__(256) void k1b_post(
    const float* __restrict__ fb, const float* __restrict__ mag,
    const float* __restrict__ adapt, double* __restrict__ adapted)
{
    __shared__ float magl[N_BINS];
    const int tid = threadIdx.x;

    for (int j = tid; j < N_BINS; j += 256) magl[j] = mag[j];
    __syncthreads();

    if (tid < N_FILTERS) {
        double acc = 0.0;
        const float* row = fb + tid * N_BINS;
        #pragma unroll 4
        for (int j = 0; j < N_BINS; ++j)
            acc += (double)row[j] * (double)magl[j];
        const double x = acc + 1e-6;               // + LATENCY_EPSILON
        const double p = pow(x, 0.3);
        const double a = p - (double)adapt[tid] * 0.5;
        adapted[tid] = a > 0.0 ? a : 0.0;          // relu
    }
}

// ============================================================================
// K2: activity = W @ adapted + b (fp64) — COALESCED, reduction hoisted.
//   R8 counters proved thread-per-row is transaction-rate-bound (108 us even
//   with W fully L3-resident, FETCH~0). New layout:
//     - one wave-load = 64 consecutive float4 = 2 complete rows (1 KB burst)
//     - wave covers 16 rows via 8 independent loads; 8 partials in regs
//     - FIVE xor-butterflies ONCE at the end, as 8 independent pipelined
//       chains (R4's mistake was 5 dependent shuffles per iteration)
//   Chunk-summation tree (offsets 1,2,4,8,16 over 32 chunks of float4
//   partials) is bit-identical to R4's k2 which passed absmax 0.
//   Grid: 4096 blocks x 256 thr (4 waves = 64 rows/block).
// ============================================================================
__global__ __launch_bounds__(256) void k2_gemv(
    const float4* __restrict__ W4, const float* __restrict__ bias,
    const double* __restrict__ adapted, double* __restrict__ activity,
    unsigned long long* __restrict__ minmax)
{
    __shared__ double ad[N_FILTERS];
    const int tid  = threadIdx.x;
    const int lane = tid & 63;
    const int half = lane >> 5;          // 0: even row of pair, 1: odd
    const int c    = lane & 31;          // float4 chunk within row

    if (tid < N_FILTERS) ad[tid] = adapted[tid];
    __syncthreads();

    const double A0 = ad[4 * c + 0];
    const double A1 = ad[4 * c + 1];
    const double A2 = ad[4 * c + 2];
    const double A3 = ad[4 * c + 3];

    const int baseRow = (blockIdx.x * 4 + (tid >> 6)) * 16;

    double part[8];
    #pragma unroll
    for (int i = 0; i < 8; ++i) {
        // 64 consecutive float4 = rows (baseRow+2i, baseRow+2i+1), 1 KB burst
        const float4 w = W4[(size_t)(baseRow + 2 * i) * 32 + lane];
        part[i] = (double)w.x * A0 + (double)w.y * A1
                + (double)w.z * A2 + (double)w.w * A3;
    }

    // 8 independent butterfly chains over the 32 chunks (xor<32 keeps halves)
    #pragma unroll
    for (int off = 1; off < 32; off <<= 1) {
        #pragma unroll
        for (int i = 0; i < 8; ++i)
            part[i] += __shfl_xor(part[i], off);
    }
    // part[i] on lane = full dot of row baseRow + 2i + half

    double mn = 1e300, mx = -1e300;
    if (c < 8) {
        const int row = baseRow + 2 * c + half;
        const double a = part[c] + (double)bias[row];
        activity[row] = a;
        mn = a;
        mx = a;
    }
    // wave-wide min/max (neutral values on non-writer lanes)
    #pragma unroll
    for (int off = 1; off < 64; off <<= 1) {
        mn = fmin(mn, __shfl_xor(mn, off));
        mx = fmax(mx, __shfl_xor(mx, off));
    }
    if (lane == 0) {
        atomicMin(&minmax[0], enc_d(mn));
        atomicMax(&minmax[1], enc_d(mx));
    }
}

// ============================================================================
// K3: latency coding + spike-matrix write (int32 out), fp64 quantization.
//   Plain int4 stores (NT regressed ~35 us — R7->R8). gridDim.y=4.
// ============================================================================
__global__ __launch_bounds__(256) void k3_spikes(
    const double* __restrict__ activity,
    const unsigned long long* __restrict__ minmax,
    int4v* __restrict__ out4)
{
    const int tid = blockIdx.x * 256 + threadIdx.x;  // 0..65535
    const double amin = dec_d(minmax[0]);
    const double amax = dec_d(minmax[1]);
    const double denom = (amax - amin) + 1e-6;

    const double nx = (activity[4 * tid + 0] - amin) / denom;
    const double ny = (activity[4 * tid + 1] - amin) / denom;
    const double nz = (activity[4 * tid + 2] - amin) / denom;
    const double nw = (activity[4 * tid + 3] - amin) / denom;

    const int lx = (int)((1.0 - nx) * 127.0);
    const int ly = (int)((1.0 - ny) * 127.0);
    const int lz = (int)((1.0 - nz) * 127.0);
    const int lw = (int)((1.0 - nw) * 127.0);

    const int vx = (nx > 0.05) ? 1 : 0;
    const int vy = (ny > 0.05) ? 1 : 0;
    const int vz = (nz > 0.05) ? 1 : 0;
    const int vw = (nw > 0.05) ? 1 : 0;

    const int t0 = blockIdx.y * (N_TIMESTEPS / 4);
    #pragma unroll 8
    for (int t = t0; t < t0 + N_TIMESTEPS / 4; ++t) {
        int4v v;
        v.x = (lx == t) ? vx : 0;
        v.y = (ly == t) ? vy : 0;
        v.z = (lz == t) ? vz : 0;
        v.w = (lw == t) ? vw : 0;
        out4[(size_t)t * (OUTPUT_SIZE / 4) + tid] = v;
    }
}

// ============================================================================
extern "C" void kernel_launch(void* const* d_in, const int* in_sizes, int n_in,
                              void* d_out, int out_size, void* d_ws, size_t ws_size,
                              hipStream_t stream) {
    (void)in_sizes; (void)n_in; (void)out_size; (void)ws_size;

    const float* audio = (const float*)d_in[0];   // [16000]
    const float* fb    = (const float*)d_in[1];   // [128, 257]
    const float* W     = (const float*)d_in[2];   // [262144, 128]
    const float* bias  = (const float*)d_in[3];   // [262144]
    const float* adapt = (const float*)d_in[4];   // [128]
    int* out = (int*)d_out;                       // [128, 262144] bool -> int32

    double* activity = (double*)d_ws;                              // 262144 f64
    unsigned long long* minmax =
        (unsigned long long*)(activity + OUTPUT_SIZE);             // 2 u64
    float* mag = (float*)(minmax + 2);                             // 257 f32
    double* adapted = (double*)(mag + 512);                        // 128 f64 (aligned)

    k1a_dft<<<N_BINS, 64, 0, stream>>>(audio, mag, minmax);
    k1b_post<<<1, 256, 0, stream>>>(fb, mag, adapt, adapted);
    k2_gemv<<<OUTPUT_SIZE / 64, 256, 0, stream>>>(
        (const float4*)W, bias, adapted, activity, minmax);
    k3_spikes<<<dim3(OUTPUT_SIZE / 4 / 256, 4), 256, 0, stream>>>(
        activity, minmax, (int4v*)out);
}